// Round 1
// baseline (9919.678 us; speedup 1.0000x reference)
//
#include <hip/hip_runtime.h>

constexpr int B  = 64;
constexpr int T  = 121;
constexpr int E  = 300;
constexpr int H  = 256;
constexpr int G4 = 1024;   // 4*H
constexpr int D  = 512;    // 2*H
constexpr int NH = 3;
constexpr int BT = B * T;  // 7744 = 121*64, divisible by 64

__device__ __forceinline__ float sigmoidf(float x) { return 1.0f / (1.0f + __expf(-x)); }
// tanh via identity 1 - 2/(e^{2x}+1); safe at +-inf (no NaN), ~few-ulp accurate.
__device__ __forceinline__ float tanhf_fast(float x) {
  float e = __expf(2.0f * x);
  return 1.0f - 2.0f / (e + 1.0f);
}

// ---------------- embedding gather: x[bt,e] = emb[tokens[bt], e] ----------------
__global__ void k_gather(const int* __restrict__ tokens, const float* __restrict__ emb,
                         float* __restrict__ x) {
  int bt = blockIdx.x;
  int tok = tokens[bt];
  const float* src = emb + (size_t)tok * E;
  float* dst = x + (size_t)bt * E;
  for (int e = threadIdx.x; e < E; e += blockDim.x) dst[e] = src[e];
}

// ---------------- generic fp32 GEMM: C = A@W (+bias) (+Cin) ----------------
// A: MxK row-major, W: KxN row-major. Requires M % 64 == 0. N,K arbitrary.
__global__ __launch_bounds__(256) void k_gemm(
    const float* __restrict__ A, const float* __restrict__ W,
    const float* __restrict__ bias, const float* __restrict__ Cin,
    float* __restrict__ C, int M, int N, int K)
{
  __shared__ float As[16][68];  // [kk][row], padded: stride 68 floats = 16B-aligned rows
  __shared__ float Ws[16][68];  // [kk][col]
  int tid = threadIdx.x;
  int tx = tid & 15, ty = tid >> 4;
  int row0 = blockIdx.y * 64, col0 = blockIdx.x * 64;
  float acc[4][4] = {};
  for (int k0 = 0; k0 < K; k0 += 16) {
#pragma unroll
    for (int i = 0; i < 4; ++i) {
      int idx = tid + i * 256;
      int kk = idx & 15, r = idx >> 4;
      int gk = k0 + kk;
      As[kk][r] = (gk < K) ? A[(size_t)(row0 + r) * K + gk] : 0.0f;
    }
#pragma unroll
    for (int i = 0; i < 4; ++i) {
      int idx = tid + i * 256;
      int c = idx & 63, kk = idx >> 6;
      int gk = k0 + kk, gc = col0 + c;
      Ws[kk][c] = (gk < K && gc < N) ? W[(size_t)gk * N + gc] : 0.0f;
    }
    __syncthreads();
#pragma unroll
    for (int k = 0; k < 16; ++k) {
      float4 av = *reinterpret_cast<const float4*>(&As[k][ty * 4]);
      float4 wv = *reinterpret_cast<const float4*>(&Ws[k][tx * 4]);
      float a4[4] = {av.x, av.y, av.z, av.w};
      float w4[4] = {wv.x, wv.y, wv.z, wv.w};
#pragma unroll
      for (int i = 0; i < 4; ++i)
#pragma unroll
        for (int j = 0; j < 4; ++j)
          acc[i][j] = fmaf(a4[i], w4[j], acc[i][j]);
    }
    __syncthreads();
  }
#pragma unroll
  for (int i = 0; i < 4; ++i) {
    int gr = row0 + ty * 4 + i;
#pragma unroll
    for (int j = 0; j < 4; ++j) {
      int gc = col0 + tx * 4 + j;
      if (gc < N) {
        float v = acc[i][j];
        if (bias) v += bias[gc];
        if (Cin)  v += Cin[(size_t)gr * N + gc];
        C[(size_t)gr * N + gc] = v;
      }
    }
  }
}

// ---------------- BiLSTM scan: one block per (batch, dir); 256 threads = hidden units ----
// facts[bt, dir*H + j]. fwd early-exits at len[b] (later steps provably masked out).
__global__ __launch_bounds__(256) void k_lstm(
    const float* __restrict__ xp_f, const float* __restrict__ xp_b,
    const float* __restrict__ Wh_f, const float* __restrict__ Wh_b,
    const int* __restrict__ lengths, float* __restrict__ facts)
{
  int b = blockIdx.x;
  int dir = blockIdx.y;
  const float* xp = dir ? xp_b : xp_f;
  const float* Wh = dir ? Wh_b : Wh_f;
  int j = threadIdx.x;
  __shared__ float hs[H];
  hs[j] = 0.0f;
  float c = 0.0f, h = 0.0f;
  int nsteps = dir ? T : lengths[b];
  __syncthreads();
  for (int s = 0; s < nsteps; ++s) {
    int t = dir ? (T - 1 - s) : s;
    const float* xrow = xp + (size_t)(b * T + t) * G4;
    float g0 = xrow[j], g1 = xrow[j + 256], g2 = xrow[j + 512], g3 = xrow[j + 768];
#pragma unroll 4
    for (int k = 0; k < H; ++k) {
      float hv = hs[k];
      const float* w = Wh + (size_t)k * G4 + j;
      g0 = fmaf(hv, w[0],   g0);
      g1 = fmaf(hv, w[256], g1);
      g2 = fmaf(hv, w[512], g2);
      g3 = fmaf(hv, w[768], g3);
    }
    float ig = sigmoidf(g0);
    float fg = sigmoidf(g1);
    float gg = tanhf_fast(g2);
    float og = sigmoidf(g3);
    c = fg * c + ig * gg;
    h = og * tanhf_fast(c);
    __syncthreads();
    hs[j] = h;
    facts[(size_t)(b * T + t) * D + dir * H + j] = h;
    __syncthreads();
  }
}

// ---------------- z halves: za = F .* v , zb = |F - v| (v = q or m) ----------------
__global__ void k_buildz(const float* __restrict__ facts, const float* __restrict__ v,
                         float* __restrict__ za, float* __restrict__ zb) {
  int bt = blockIdx.x;
  int b = bt / T;
  const float* F = facts + (size_t)bt * D;
  const float* vb = v + (size_t)b * D;
  for (int d = threadIdx.x; d < D; d += blockDim.x) {
    float f = F[d], vv = vb[d];
    za[(size_t)bt * D + d] = f * vv;
    zb[(size_t)bt * D + d] = fabsf(f - vv);
  }
}

// ---------------- score: s[bt] = b2 + sum_e tanh(att_h[bt,e]) * W2[e] ----------------
__global__ void k_score(const float* __restrict__ att_h, const float* __restrict__ W2,
                        const float* __restrict__ b2, float* __restrict__ s) {
  int bt = blockIdx.x;
  int tid = threadIdx.x;  // 64
  float acc = 0.f;
  for (int e = tid; e < E; e += 64)
    acc += tanhf_fast(att_h[(size_t)bt * E + e]) * W2[e];
  for (int off = 32; off > 0; off >>= 1) acc += __shfl_down(acc, off);
  if (tid == 0) s[bt] = acc + b2[0];
}

// ---------------- masked softmax over t ----------------
__global__ void k_softmax(const float* __restrict__ s, const int* __restrict__ lengths,
                          float* __restrict__ a) {
  int b = blockIdx.x;
  int t = threadIdx.x;  // 128
  int len = lengths[b];
  __shared__ float wred[2];
  float val = -1e30f;
  if (t < T) val = (t < len) ? s[b * T + t] : -1e9f;
  float mx = val;
  for (int off = 32; off > 0; off >>= 1) mx = fmaxf(mx, __shfl_xor(mx, off));
  int wid = t >> 6, lane = t & 63;
  if (lane == 0) wred[wid] = mx;
  __syncthreads();
  mx = fmaxf(wred[0], wred[1]);
  __syncthreads();
  float e = (t < T && t < len) ? __expf(val - mx) : 0.0f;
  float sum = e;
  for (int off = 32; off > 0; off >>= 1) sum += __shfl_xor(sum, off);
  if (lane == 0) wred[wid] = sum;
  __syncthreads();
  float tot = wred[0] + wred[1];
  if (t < T) a[b * T + t] = e / tot;
}

// ---------------- attention GRU scan: one block per batch, 512 threads = units -------
// steps with t >= len have a==0 exactly -> h unchanged -> early exit.
__global__ __launch_bounds__(512) void k_gru(
    const float* __restrict__ xr, const float* __restrict__ xc,
    const float* __restrict__ Ur, const float* __restrict__ Uc,
    const float* __restrict__ br, const float* __restrict__ bc,
    const float* __restrict__ att, const int* __restrict__ lengths,
    float* __restrict__ ep)
{
  int b = blockIdx.x;
  int j = threadIdx.x;
  __shared__ float hs[D];
  hs[j] = 0.0f;
  float hj = 0.0f;
  int len = lengths[b];
  __syncthreads();
  for (int t = 0; t < len; ++t) {
    float racc = 0.f, cacc = 0.f;
#pragma unroll 4
    for (int k = 0; k < D; ++k) {
      float hv = hs[k];
      racc = fmaf(hv, Ur[(size_t)k * D + j], racc);
      cacc = fmaf(hv, Uc[(size_t)k * D + j], cacc);
    }
    size_t base = (size_t)(b * T + t) * D;
    float r  = sigmoidf(xr[base + j] + racc + br[j]);
    float hc = tanhf_fast(xc[base + j] + r * cacc + bc[j]);
    float g = att[b * T + t];
    hj = g * hc + (1.f - g) * hj;
    __syncthreads();
    hs[j] = hj;
    __syncthreads();
  }
  ep[(size_t)b * D + j] = hj;
}

// ---------------- hop projection: m_out = relu([m, ep, q] @ Whop + bhop) ----------------
__global__ __launch_bounds__(512) void k_hop(
    const float* __restrict__ m_in, const float* __restrict__ ep,
    const float* __restrict__ q, const float* __restrict__ Whop,
    const float* __restrict__ bhop, float* __restrict__ m_out)
{
  int b = blockIdx.x, j = threadIdx.x;
  __shared__ float av[3 * D];
  av[j]         = m_in[(size_t)b * D + j];
  av[D + j]     = ep[(size_t)b * D + j];
  av[2 * D + j] = q[(size_t)b * D + j];
  __syncthreads();
  float acc = bhop[j];
#pragma unroll 4
  for (int k = 0; k < 3 * D; ++k)
    acc = fmaf(av[k], Whop[(size_t)k * D + j], acc);
  m_out[(size_t)b * D + j] = fmaxf(acc, 0.0f);
}

// ---------------- output: out[b] = sigmoid([m,q] @ Wo + bo) ----------------
__global__ void k_out(const float* __restrict__ m, const float* __restrict__ q,
                      const float* __restrict__ Wo, const float* __restrict__ bo,
                      float* __restrict__ out)
{
  int b = blockIdx.x, tid = threadIdx.x;  // 256
  float acc = 0.f;
  for (int k = tid; k < D; k += 256)
    acc += m[(size_t)b * D + k] * Wo[k] + q[(size_t)b * D + k] * Wo[D + k];
  for (int off = 32; off > 0; off >>= 1) acc += __shfl_down(acc, off);
  __shared__ float red[4];
  int wid = tid >> 6, lane = tid & 63;
  if (lane == 0) red[wid] = acc;
  __syncthreads();
  if (tid == 0) {
    float tot = red[0] + red[1] + red[2] + red[3];
    out[b] = 1.0f / (1.0f + __expf(-(tot + bo[0])));
  }
}

extern "C" void kernel_launch(void* const* d_in, const int* in_sizes, int n_in,
                              void* d_out, int out_size, void* d_ws, size_t ws_size,
                              hipStream_t stream)
{
  const int*   tokens  = (const int*)d_in[0];
  const int*   lengths = (const int*)d_in[1];
  const float* emb     = (const float*)d_in[2];
  const float* Wx_f    = (const float*)d_in[3];
  const float* Wh_f    = (const float*)d_in[4];
  const float* b_f     = (const float*)d_in[5];
  const float* Wx_b    = (const float*)d_in[6];
  const float* Wh_b    = (const float*)d_in[7];
  const float* b_b     = (const float*)d_in[8];
  const float* W1      = (const float*)d_in[9];
  const float* b1      = (const float*)d_in[10];
  const float* W2      = (const float*)d_in[11];
  const float* b2      = (const float*)d_in[12];
  const float* Wr      = (const float*)d_in[13];
  const float* Ur      = (const float*)d_in[14];
  const float* br      = (const float*)d_in[15];
  const float* Wc      = (const float*)d_in[16];
  const float* Uc      = (const float*)d_in[17];
  const float* bc      = (const float*)d_in[18];
  const float* q       = (const float*)d_in[19];
  const float* W_hops  = (const float*)d_in[20];
  const float* b_hops  = (const float*)d_in[21];
  const float* Wo      = (const float*)d_in[22];
  const float* bo      = (const float*)d_in[23];
  float* ws = (float*)d_ws;

  // workspace layout (floats); xp_f/xp_b/x regions are reused after the LSTM.
  float* x      = ws;                          // BT*E   (later: part0)
  float* xp_f   = x + (size_t)BT * E;          // BT*G4  (later: xr | xc)
  float* xp_b   = xp_f + (size_t)BT * G4;      // BT*G4  (later: za | zb)
  float* facts  = xp_b + (size_t)BT * G4;      // BT*D
  float* att_h  = facts + (size_t)BT * D;      // BT*E
  float* scores = att_h + (size_t)BT * E;      // BT
  float* att    = scores + BT;                 // BT
  float* m0     = att + BT;                    // B*D
  float* m1     = m0 + (size_t)B * D;          // B*D
  float* epb    = m1 + (size_t)B * D;          // B*D
  float* xr     = xp_f;                        // BT*D
  float* xc     = xp_f + (size_t)BT * D;       // BT*D
  float* za     = xp_b;                        // BT*D
  float* zb     = xp_b + (size_t)BT * D;       // BT*D
  float* part0  = x;                           // BT*E

  // 1) embed + input projections
  k_gather<<<BT, 256, 0, stream>>>(tokens, emb, x);
  k_gemm<<<dim3(16, 121), 256, 0, stream>>>(x, Wx_f, b_f, nullptr, xp_f, BT, G4, E);
  k_gemm<<<dim3(16, 121), 256, 0, stream>>>(x, Wx_b, b_b, nullptr, xp_b, BT, G4, E);
  // 2) BiLSTM
  k_lstm<<<dim3(B, 2), 256, 0, stream>>>(xp_f, xp_b, Wh_f, Wh_b, lengths, facts);
  // 3) hop-invariant precomputes
  k_gemm<<<dim3(8, 121), 256, 0, stream>>>(facts, Wr, nullptr, nullptr, xr, BT, D, D);
  k_gemm<<<dim3(8, 121), 256, 0, stream>>>(facts, Wc, nullptr, nullptr, xc, BT, D, D);
  k_buildz<<<BT, 512, 0, stream>>>(facts, q, za, zb);
  k_gemm<<<dim3(5, 121), 256, 0, stream>>>(za, W1, b1, nullptr, part0, BT, E, D);
  k_gemm<<<dim3(5, 121), 256, 0, stream>>>(zb, W1 + (size_t)1024 * E, nullptr, part0, part0, BT, E, D);

  // 4) hops
  const float* m_in = q;
  float* mb[2] = {m0, m1};
  for (int i = 0; i < NH; ++i) {
    k_buildz<<<BT, 512, 0, stream>>>(facts, m_in, za, zb);
    k_gemm<<<dim3(5, 121), 256, 0, stream>>>(za, W1 + (size_t)512 * E, nullptr, part0, att_h, BT, E, D);
    k_gemm<<<dim3(5, 121), 256, 0, stream>>>(zb, W1 + (size_t)1536 * E, nullptr, att_h, att_h, BT, E, D);
    k_score<<<BT, 64, 0, stream>>>(att_h, W2, b2, scores);
    k_softmax<<<B, 128, 0, stream>>>(scores, lengths, att);
    k_gru<<<B, 512, 0, stream>>>(xr, xc, Ur, Uc, br, bc, att, lengths, epb);
    k_hop<<<B, 512, 0, stream>>>(m_in, epb, q,
                                 W_hops + (size_t)i * 3 * D * D, b_hops + (size_t)i * D,
                                 mb[i & 1]);
    m_in = mb[i & 1];
  }
  // 5) output
  k_out<<<B, 256, 0, stream>>>(m_in, q, Wo, bo, (float*)d_out);
}